// Round 9
// baseline (52.043 us; speedup 1.0000x reference)
//
#include <hip/hip_runtime.h>
#include <math.h>

#define FFT_N   4096
#define NT      256
// FFT-stage index map: +1 f2 per 16 -> stride-256 stage accesses at the b64 floor.
#define PHYS(i) ((i) + ((i) >> 4))
// Epilogue index map: +1 f2 per 8 -> the epilogue's stride-8-across-lanes reads
// land at odd physical stride 9 (gcd(9,16)=1: all bank-pairs covered, at-floor).
#define EPI(i)  ((i) + ((i) >> 3))
#define LDS_SZ  4608   // max(PHYS(4350)+1, EPI(4095)+1) = 4607 -> 36864 B

// ext_vector float2 so clang lowers complex arithmetic to packed-fp32.
typedef float f2 __attribute__((ext_vector_type(2)));

__device__ __forceinline__ f2 cmul(f2 a, f2 b) {
    return (f2){a.x, a.x} * b + (f2){-a.y, a.y} * (f2){b.y, b.x};
}

// In-place 4-point DFT (w4 = -i); adds/subs are single pk ops.
__device__ __forceinline__ void dft4(f2& a, f2& b, f2& c, f2& d) {
    f2 t0 = a + c;
    f2 t1 = a - c;
    f2 t2 = b + d;
    f2 s  = b - d;
    f2 t3 = (f2){s.y, -s.x};  // -i*(b-d)
    a = t0 + t2;
    b = t1 + t3;
    c = t0 - t2;
    d = t1 - t3;
}

// 16-point DFT in registers via radix-4 x radix-4.
// Output DFT16[q1 + 4*q2] lands in v[4*q1 + q2] (reg = ((q&3)<<2)|(q>>2)).
__device__ __forceinline__ void dft16(f2 v[16]) {
    #pragma unroll
    for (int r1 = 0; r1 < 4; ++r1)
        dft4(v[r1], v[r1 + 4], v[r1 + 8], v[r1 + 12]);

    const float C1 = 0.92387953251128675613f;  // cos(pi/8)
    const float S1 = 0.38268343236508977173f;  // sin(pi/8)
    const float R2 = 0.70710678118654752440f;  // sqrt(2)/2
    v[5]  = cmul(v[5],  (f2){ C1, -S1});   // w16^1
    v[9]  = cmul(v[9],  (f2){ R2, -R2});   // w16^2
    v[13] = cmul(v[13], (f2){ S1, -C1});   // w16^3
    v[6]  = cmul(v[6],  (f2){ R2, -R2});   // w16^2
    v[10] = (f2){v[10].y, -v[10].x};       // w16^4 = -i
    v[14] = cmul(v[14], (f2){-R2, -R2});   // w16^6
    v[7]  = cmul(v[7],  (f2){ S1, -C1});   // w16^3
    v[11] = cmul(v[11], (f2){-R2, -R2});   // w16^6
    v[15] = cmul(v[15], (f2){-C1,  S1});   // w16^9
    #pragma unroll
    for (int q1 = 0; q1 < 4; ++q1)
        dft4(v[4 * q1], v[4 * q1 + 1], v[4 * q1 + 2], v[4 * q1 + 3]);
}

// Stage store with inter-stage twiddles built log-depth (dep chain ~4 deep).
template <int M>
__device__ __forceinline__ void store_stage_tw(f2* buf, int tid, f2 v[16]) {
    const int j = tid / M;
    const int k = tid % M;
    const int obase = j * 16 * M + k;
    float sn, cs;
    __sincosf((float)j * (-6.28318530717958647692f * (float)M / (float)FFT_N), &sn, &cs);
    f2 w[16];
    w[1]  = (f2){cs, sn};
    w[2]  = cmul(w[1], w[1]);
    w[3]  = cmul(w[2], w[1]);
    w[4]  = cmul(w[2], w[2]);
    w[5]  = cmul(w[4], w[1]);
    w[6]  = cmul(w[4], w[2]);
    w[7]  = cmul(w[4], w[3]);
    w[8]  = cmul(w[4], w[4]);
    w[9]  = cmul(w[8], w[1]);
    w[10] = cmul(w[8], w[2]);
    w[11] = cmul(w[8], w[3]);
    w[12] = cmul(w[8], w[4]);
    w[13] = cmul(w[8], w[5]);
    w[14] = cmul(w[8], w[6]);
    w[15] = cmul(w[8], w[7]);
    buf[PHYS(obase)] = v[0];
    #pragma unroll
    for (int q = 1; q < 16; ++q) {
        const int reg = ((q & 3) << 2) | (q >> 2);
        buf[PHYS(obase + q * M)] = cmul(v[reg], w[q]);
    }
}

__device__ __forceinline__ void load_stage(const f2* buf, int tid, f2 v[16]) {
    #pragma unroll
    for (int r = 0; r < 16; ++r) v[r] = buf[PHYS(tid + 256 * r)];
}

// One block per PAIR of windows: z = x1 + i*x2, one 4096-pt complex FFT,
// unpack |F1|^2,|F2|^2 via conjugate symmetry. ROUND 9: stage 3 deposits Z in
// an EPI-mapped LDS layout; each thread then computes 9 consecutive bins
// k=8t..8t+8 and writes BOTH the forward block [8t..8t+7] and the reversed
// mirror block [4088-8t..4095-8t] as aligned float4 stores (16 B/lane).
__global__ __launch_bounds__(NT) void spec_fft_kernel(const float* __restrict__ x,
                                                      float* __restrict__ out) {
    __shared__ f2 buf[LDS_SZ];
    const int t = threadIdx.x;
    const size_t base = (size_t)blockIdx.x * (2 * FFT_N);
    const float* __restrict__ x1 = x + base + t;
    const float* __restrict__ x2 = x + base + FFT_N + t;

    f2 v[16];
    #pragma unroll
    for (int r = 0; r < 16; ++r)
        v[r] = (f2){x1[256 * r], x2[256 * r]};

    // Stage 1 (M=1)
    dft16(v);
    store_stage_tw<1>(buf, t, v);
    __syncthreads();

    // Stage 2 (M=16)
    load_stage(buf, t, v);
    __syncthreads();
    dft16(v);
    store_stage_tw<16>(buf, t, v);
    __syncthreads();

    // Stage 3 (M=256): j==0 -> no twiddles. Thread t holds Z[t+256q] in
    // v[reg(q)]; deposit ALL of Z via the EPI map for the epilogue.
    load_stage(buf, t, v);
    __syncthreads();
    dft16(v);
    #pragma unroll
    for (int q = 0; q < 16; ++q) {
        const int reg = ((q & 3) << 2) | (q >> 2);
        buf[EPI(t + 256 * q)] = v[reg];
    }
    __syncthreads();

    // Epilogue: thread t covers k = 8t..8t+8 (9 bins; neighbors overlap by 1).
    // F1(k)=(Z(k)+conj(Z(N-k)))/2, F2(k)=(Z(k)-conj(Z(N-k)))/(2i);
    // real input -> P(N-k)=P(k). k=0 and k=2048 self-mirrors fall out of the
    // same formula (m==k -> e1=(2Re,0), e2=(0,2Im)).
    float* __restrict__ o1 = out + base;
    float* __restrict__ o2 = o1 + FFT_N;
    const int k0 = 8 * t;
    float p1[9], p2[9];
    #pragma unroll
    for (int c = 0; c < 9; ++c) {
        const int k = k0 + c;
        const int m = (FFT_N - k) & (FFT_N - 1);
        f2 zk = buf[EPI(k)];
        f2 zn = buf[EPI(m)];
        f2 zc = (f2){zn.x, -zn.y};       // conj(Z(N-k))
        f2 e1 = zk + zc;                  // 2*F1
        f2 e2 = zk - zc;                  // 2i*F2 (same magnitude as 2*F2)
        p1[c] = 0.25f * (e1.x * e1.x + e1.y * e1.y);
        p2[c] = 0.25f * (e2.x * e2.x + e2.y * e2.y);
    }
    // Forward half [0,2048): aligned float4 stores.
    *(float4*)(o1 + k0)     = make_float4(p1[0], p1[1], p1[2], p1[3]);
    *(float4*)(o1 + k0 + 4) = make_float4(p1[4], p1[5], p1[6], p1[7]);
    *(float4*)(o2 + k0)     = make_float4(p2[0], p2[1], p2[2], p2[3]);
    *(float4*)(o2 + k0 + 4) = make_float4(p2[4], p2[5], p2[6], p2[7]);
    // Mirror half [2048,4096): position mb+i holds P(4096-mb-i) = p[8-i].
    const int mb = FFT_N - k0 - 8;  // 4088 - 8t; t=0..255 tiles [2048,4095] exactly
    *(float4*)(o1 + mb)     = make_float4(p1[8], p1[7], p1[6], p1[5]);
    *(float4*)(o1 + mb + 4) = make_float4(p1[4], p1[3], p1[2], p1[1]);
    *(float4*)(o2 + mb)     = make_float4(p2[8], p2[7], p2[6], p2[5]);
    *(float4*)(o2 + mb + 4) = make_float4(p2[4], p2[3], p2[2], p2[1]);
}

extern "C" void kernel_launch(void* const* d_in, const int* in_sizes, int n_in,
                              void* d_out, int out_size, void* d_ws, size_t ws_size,
                              hipStream_t stream) {
    const float* x = (const float*)d_in[0];
    float* out = (float*)d_out;
    const int B = in_sizes[0] / FFT_N;  // 8192
    spec_fft_kernel<<<B / 2, NT, 0, stream>>>(x, out);
}

// Round 10
// 47.007 us; speedup vs baseline: 1.1071x; 1.1071x over previous
//
#include <hip/hip_runtime.h>
#include <math.h>

#define FFT_N   4096
#define NT      256
// Half-buffer padded index, i in [0,2048): +1 f2 per 16 keeps strided store
// phases at ~2 lanes/bank-pair and contiguous loads conflict-free.
#define HP(i)   ((i) + ((i) >> 4))
#define LDS_SZ  2176   // HP(2047)=2174 -> 17408 B; 8-9 blocks/CU by LDS
#define REG(q)  ((((q) & 3) << 2) | ((q) >> 2))

// ext_vector float2 so clang lowers complex arithmetic to packed-fp32.
typedef float f2 __attribute__((ext_vector_type(2)));

__device__ __forceinline__ f2 cmul(f2 a, f2 b) {
    return (f2){a.x, a.x} * b + (f2){-a.y, a.y} * (f2){b.y, b.x};
}

// In-place 4-point DFT (w4 = -i).
__device__ __forceinline__ void dft4(f2& a, f2& b, f2& c, f2& d) {
    f2 t0 = a + c;
    f2 t1 = a - c;
    f2 t2 = b + d;
    f2 s  = b - d;
    f2 t3 = (f2){s.y, -s.x};  // -i*(b-d)
    a = t0 + t2;
    b = t1 + t3;
    c = t0 - t2;
    d = t1 - t3;
}

// 16-point DFT in registers via radix-4 x radix-4.
// Input v[r] = c_r. Output DFT16[q] lands in v[REG(q)].
__device__ __forceinline__ void dft16(f2 v[16]) {
    #pragma unroll
    for (int r1 = 0; r1 < 4; ++r1)
        dft4(v[r1], v[r1 + 4], v[r1 + 8], v[r1 + 12]);

    const float C1 = 0.92387953251128675613f;  // cos(pi/8)
    const float S1 = 0.38268343236508977173f;  // sin(pi/8)
    const float R2 = 0.70710678118654752440f;  // sqrt(2)/2
    v[5]  = cmul(v[5],  (f2){ C1, -S1});   // w16^1
    v[9]  = cmul(v[9],  (f2){ R2, -R2});   // w16^2
    v[13] = cmul(v[13], (f2){ S1, -C1});   // w16^3
    v[6]  = cmul(v[6],  (f2){ R2, -R2});   // w16^2
    v[10] = (f2){v[10].y, -v[10].x};       // w16^4 = -i
    v[14] = cmul(v[14], (f2){-R2, -R2});   // w16^6
    v[7]  = cmul(v[7],  (f2){ S1, -C1});   // w16^3
    v[11] = cmul(v[11], (f2){-R2, -R2});   // w16^6
    v[15] = cmul(v[15], (f2){-C1,  S1});   // w16^9
    #pragma unroll
    for (int q1 = 0; q1 < 4; ++q1)
        dft4(v[4 * q1], v[4 * q1 + 1], v[4 * q1 + 2], v[4 * q1 + 3]);
}

// Apply inter-stage twiddles w^q (w = exp(-2pi*i*j*M/N), j = t/M) in place to
// v[REG(q)]. Log-depth products; w-chain dies here (keeps VGPR peak low).
template <int M>
__device__ __forceinline__ void twiddle_inplace(int t, f2 v[16]) {
    const int j = t / M;
    float sn, cs;
    __sincosf((float)j * (-6.28318530717958647692f * (float)M / (float)FFT_N), &sn, &cs);
    const f2 w1 = (f2){cs, sn};
    const f2 w2 = cmul(w1, w1);
    const f2 w3 = cmul(w2, w1);
    const f2 w4 = cmul(w2, w2);
    const f2 w5 = cmul(w4, w1);
    const f2 w6 = cmul(w4, w2);
    const f2 w7 = cmul(w4, w3);
    const f2 w8 = cmul(w4, w4);
    v[4]  = cmul(v[4],  w1);            // q=1
    v[8]  = cmul(v[8],  w2);            // q=2
    v[12] = cmul(v[12], w3);            // q=3
    v[1]  = cmul(v[1],  w4);            // q=4
    v[5]  = cmul(v[5],  w5);            // q=5
    v[9]  = cmul(v[9],  w6);            // q=6
    v[13] = cmul(v[13], w7);            // q=7
    v[2]  = cmul(v[2],  w8);            // q=8
    v[6]  = cmul(v[6],  cmul(w8, w1));  // q=9
    v[10] = cmul(v[10], cmul(w8, w2));  // q=10
    v[14] = cmul(v[14], cmul(w8, w3));  // q=11
    v[3]  = cmul(v[3],  cmul(w8, w4));  // q=12
    v[7]  = cmul(v[7],  cmul(w8, w5));  // q=13
    v[11] = cmul(v[11], cmul(w8, w6));  // q=14
    v[15] = cmul(v[15], cmul(w8, w7));  // q=15
}

// One block per PAIR of windows: z = x1 + i*x2, one 4096-pt complex FFT as
// 3 radix-16 Stockham stages; |F1|^2,|F2|^2 via conjugate symmetry with the
// symmetric-output trick. Each inter-stage exchange runs through a HALF-SIZE
// (2048-pt) LDS buffer in two address-half phases: store-owner split t<128 is
// wave-uniform; stage-s store indices for t<128 lie entirely in [0,2048).
// 17 KB LDS -> ~8 blocks/CU resident at staggered phases (convoy breaking).
__global__ __launch_bounds__(NT) void spec_fft_kernel(const float* __restrict__ x,
                                                      float* __restrict__ out) {
    __shared__ f2 buf[LDS_SZ];
    const int t = threadIdx.x;
    const size_t base = (size_t)blockIdx.x * (2 * FFT_N);
    const float* __restrict__ x1 = x + base + t;
    const float* __restrict__ x2 = x + base + FFT_N + t;

    f2 v[16], u[16];
    #pragma unroll
    for (int r = 0; r < 16; ++r)
        v[r] = (f2){x1[256 * r], x2[256 * r]};

    // ---- Stage 1 (M=1): out index 16t+q ----
    dft16(v);
    twiddle_inplace<1>(t, v);
    if (t < 128) {                       // lower half [0,2048)
        #pragma unroll
        for (int q = 0; q < 16; ++q) buf[HP(16 * t + q)] = v[REG(q)];
    }
    __syncthreads();
    #pragma unroll
    for (int r = 0; r < 8; ++r) u[r] = buf[HP(t + 256 * r)];
    __syncthreads();
    if (t >= 128) {                      // upper half [2048,4096)
        #pragma unroll
        for (int q = 0; q < 16; ++q) buf[HP(16 * t + q - 2048)] = v[REG(q)];
    }
    __syncthreads();
    #pragma unroll
    for (int r = 8; r < 16; ++r) u[r] = buf[HP(t + 256 * (r - 8))];
    __syncthreads();

    // ---- Stage 2 (M=16): out index 256*(t/16) + (t%16) + 16q ----
    dft16(u);
    twiddle_inplace<16>(t, u);
    const int ob2 = ((t >> 4) << 8) + (t & 15);
    if (t < 128) {
        #pragma unroll
        for (int q = 0; q < 16; ++q) buf[HP(ob2 + 16 * q)] = u[REG(q)];
    }
    __syncthreads();
    #pragma unroll
    for (int r = 0; r < 8; ++r) v[r] = buf[HP(t + 256 * r)];
    __syncthreads();
    if (t >= 128) {
        #pragma unroll
        for (int q = 0; q < 16; ++q) buf[HP(ob2 + 16 * q - 2048)] = u[REG(q)];
    }
    __syncthreads();
    #pragma unroll
    for (int r = 8; r < 16; ++r) v[r] = buf[HP(t + 256 * (r - 8))];
    __syncthreads();

    // ---- Stage 3 (M=256): j==0 -> no twiddles. Thread t holds Z[t+256q] in
    // v[REG(q)]. Epilogue mirrors live in the UPPER half [2048,4096) (plus
    // the k=0 self-mirror) -> one half-buffer phase.
    dft16(v);
    #pragma unroll
    for (int q = 8; q < 16; ++q) buf[HP(t + 256 * q - 2048)] = v[REG(q)];
    __syncthreads();

    // F1(k)=(Z(k)+conj(Z(N-k)))/2, F2(k)=(Z(k)-conj(Z(N-k)))/(2i);
    // real inputs -> P(N-k)=P(k): compute k<2048, store both halves.
    float* __restrict__ o1 = out + base;
    float* __restrict__ o2 = o1 + FFT_N;
    #pragma unroll
    for (int q = 0; q < 8; ++q) {
        const int k = t + 256 * q;
        const int m = (FFT_N - k) & (FFT_N - 1);
        const int mi = (k == 0) ? 0 : (2048 - t - 256 * q);  // m-2048 in half-buf
        f2 zk = v[REG(q)];
        f2 zn = buf[HP(mi)];
        if (k == 0) zn = zk;              // bin 0 self-mirror
        f2 zc = (f2){zn.x, -zn.y};        // conj(Z(N-k))
        f2 e1 = zk + zc;                  // 2*F1
        f2 e2 = zk - zc;                  // 2i*F2 (same magnitude as 2*F2)
        float p1 = 0.25f * (e1.x * e1.x + e1.y * e1.y);
        float p2 = 0.25f * (e2.x * e2.x + e2.y * e2.y);
        o1[k] = p1;
        o2[k] = p2;
        o1[m] = p1;  // k=0: same addr, same value
        o2[m] = p2;
    }
    if (t == 0) {  // bin 2048 self-mirror: Z[2048] sits at half-buf index 0
        f2 z = buf[HP(0)];
        o1[2048] = z.x * z.x;
        o2[2048] = z.y * z.y;
    }
}

extern "C" void kernel_launch(void* const* d_in, const int* in_sizes, int n_in,
                              void* d_out, int out_size, void* d_ws, size_t ws_size,
                              hipStream_t stream) {
    const float* x = (const float*)d_in[0];
    float* out = (float*)d_out;
    const int B = in_sizes[0] / FFT_N;  // 8192
    spec_fft_kernel<<<B / 2, NT, 0, stream>>>(x, out);
}

// Round 11
// 46.426 us; speedup vs baseline: 1.1210x; 1.0125x over previous
//
#include <hip/hip_runtime.h>
#include <math.h>

#define FFT_N   4096
#define NT      256
// Padded LDS index: +1 f2 per 16 keeps every stage's strided access at the
// wave64 b64 floor. For j<4 and i%4==0: PHYS(i+j)==PHYS(i)+j (staging b128 ok).
#define PHYS(i) ((i) + ((i) >> 4))
#define LDS_SZ  (FFT_N + FFT_N / 16)

// ext_vector float2 so clang lowers complex arithmetic to packed-fp32.
typedef float f2 __attribute__((ext_vector_type(2)));

__device__ __forceinline__ f2 cmul(f2 a, f2 b) {
    return (f2){a.x, a.x} * b + (f2){-a.y, a.y} * (f2){b.y, b.x};
}

// In-place 4-point DFT (w4 = -i); adds/subs are single pk ops.
__device__ __forceinline__ void dft4(f2& a, f2& b, f2& c, f2& d) {
    f2 t0 = a + c;
    f2 t1 = a - c;
    f2 t2 = b + d;
    f2 s  = b - d;
    f2 t3 = (f2){s.y, -s.x};  // -i*(b-d)
    a = t0 + t2;
    b = t1 + t3;
    c = t0 - t2;
    d = t1 - t3;
}

// 16-point DFT in registers via radix-4 x radix-4.
// Output DFT16[q1 + 4*q2] lands in v[4*q1 + q2] (reg = ((q&3)<<2)|(q>>2)).
__device__ __forceinline__ void dft16(f2 v[16]) {
    #pragma unroll
    for (int r1 = 0; r1 < 4; ++r1)
        dft4(v[r1], v[r1 + 4], v[r1 + 8], v[r1 + 12]);

    const float C1 = 0.92387953251128675613f;  // cos(pi/8)
    const float S1 = 0.38268343236508977173f;  // sin(pi/8)
    const float R2 = 0.70710678118654752440f;  // sqrt(2)/2
    v[5]  = cmul(v[5],  (f2){ C1, -S1});   // w16^1
    v[9]  = cmul(v[9],  (f2){ R2, -R2});   // w16^2
    v[13] = cmul(v[13], (f2){ S1, -C1});   // w16^3
    v[6]  = cmul(v[6],  (f2){ R2, -R2});   // w16^2
    v[10] = (f2){v[10].y, -v[10].x};       // w16^4 = -i
    v[14] = cmul(v[14], (f2){-R2, -R2});   // w16^6
    v[7]  = cmul(v[7],  (f2){ S1, -C1});   // w16^3
    v[11] = cmul(v[11], (f2){-R2, -R2});   // w16^6
    v[15] = cmul(v[15], (f2){-C1,  S1});   // w16^9
    #pragma unroll
    for (int q1 = 0; q1 < 4; ++q1)
        dft4(v[4 * q1], v[4 * q1 + 1], v[4 * q1 + 2], v[4 * q1 + 3]);
}

// Stage store with inter-stage twiddles built log-depth (dep chain ~4 deep).
template <int M>
__device__ __forceinline__ void store_stage_tw(f2* buf, int tid, f2 v[16]) {
    const int j = tid / M;
    const int k = tid % M;
    const int obase = j * 16 * M + k;
    float sn, cs;
    __sincosf((float)j * (-6.28318530717958647692f * (float)M / (float)FFT_N), &sn, &cs);
    f2 w[16];
    w[1]  = (f2){cs, sn};
    w[2]  = cmul(w[1], w[1]);
    w[3]  = cmul(w[2], w[1]);
    w[4]  = cmul(w[2], w[2]);
    w[5]  = cmul(w[4], w[1]);
    w[6]  = cmul(w[4], w[2]);
    w[7]  = cmul(w[4], w[3]);
    w[8]  = cmul(w[4], w[4]);
    w[9]  = cmul(w[8], w[1]);
    w[10] = cmul(w[8], w[2]);
    w[11] = cmul(w[8], w[3]);
    w[12] = cmul(w[8], w[4]);
    w[13] = cmul(w[8], w[5]);
    w[14] = cmul(w[8], w[6]);
    w[15] = cmul(w[8], w[7]);
    buf[PHYS(obase)] = v[0];
    #pragma unroll
    for (int q = 1; q < 16; ++q) {
        const int reg = ((q & 3) << 2) | (q >> 2);
        buf[PHYS(obase + q * M)] = cmul(v[reg], w[q]);
    }
}

__device__ __forceinline__ void load_stage(const f2* buf, int tid, f2 v[16]) {
    #pragma unroll
    for (int r = 0; r < 16; ++r) v[r] = buf[PHYS(tid + 256 * r)];
}

// One block per PAIR of windows: z = x1 + i*x2, one 4096-pt complex FFT,
// unpack |F1|^2, |F2|^2 via conjugate symmetry + symmetric-output store.
// ROUND 11 A/B vs r7: input read as float4 (16 B/lane, the m13 copy-ceiling
// width) through an LDS staging pass, instead of direct dword gathers.
// Everything else identical to the 46.7 us r7 kernel.
__global__ __launch_bounds__(NT) void spec_fft_kernel(const float* __restrict__ x,
                                                      float* __restrict__ out) {
    __shared__ f2 buf[LDS_SZ];
    const int t = threadIdx.x;
    const size_t base = (size_t)blockIdx.x * (2 * FFT_N);
    const float4* __restrict__ X1 = (const float4*)(x + base);
    const float4* __restrict__ X2 = (const float4*)(x + base + FFT_N);

    // Staging: 8 float4 loads/thread, interleave into LDS as z = x1 + i*x2.
    #pragma unroll
    for (int it = 0; it < 4; ++it) {
        const int i = t + 256 * it;   // float4 index within the window
        float4 a = X1[i];
        float4 b = X2[i];
        const int p = PHYS(4 * i);    // 4*i % 16 in {0,4,8,12} -> no pad crossing
        buf[p + 0] = (f2){a.x, b.x};
        buf[p + 1] = (f2){a.y, b.y};
        buf[p + 2] = (f2){a.z, b.z};
        buf[p + 3] = (f2){a.w, b.w};
    }
    __syncthreads();

    f2 v[16];
    load_stage(buf, t, v);
    __syncthreads();

    // Stage 1 (M=1)
    dft16(v);
    store_stage_tw<1>(buf, t, v);
    __syncthreads();

    // Stage 2 (M=16)
    load_stage(buf, t, v);
    __syncthreads();
    dft16(v);
    store_stage_tw<16>(buf, t, v);
    __syncthreads();

    // Stage 3 (M=256): j==0 -> no twiddles. Thread t ends holding Z[t+256q]
    // in v[reg(q)]. Only q=0 and q>=8 are ever read back as mirrors.
    load_stage(buf, t, v);
    __syncthreads();
    dft16(v);
    buf[PHYS(t)] = v[0];  // reg(0)=0; needed as mirror of k=t (q=0 outputs)
    #pragma unroll
    for (int q = 8; q < 16; ++q) {
        const int reg = ((q & 3) << 2) | (q >> 2);
        buf[PHYS(t + 256 * q)] = v[reg];
    }
    __syncthreads();

    // Fused symmetric epilogue over k = t + 256q, q < 8 (k in [0, 2048)):
    // F1(k)=(Z(k)+conj(Z(N-k)))/2, F2(k)=(Z(k)-conj(Z(N-k)))/(2i);
    // real input -> P(N-k)=P(k), store both halves.
    float* __restrict__ o1 = out + base;
    float* __restrict__ o2 = o1 + FFT_N;
    #pragma unroll
    for (int q = 0; q < 8; ++q) {
        const int reg = ((q & 3) << 2) | (q >> 2);
        const int k = t + 256 * q;
        const int m = (FFT_N - k) & (FFT_N - 1);
        f2 zk = v[reg];
        f2 zn = buf[PHYS(m)];
        f2 zc = (f2){zn.x, -zn.y};       // conj(Z(N-k))
        f2 e1 = zk + zc;                  // 2*F1
        f2 e2 = zk - zc;                  // 2i*F2 (same magnitude as 2*F2)
        float p1 = 0.25f * (e1.x * e1.x + e1.y * e1.y);
        float p2 = 0.25f * (e2.x * e2.x + e2.y * e2.y);
        o1[k] = p1;
        o2[k] = p2;
        o1[m] = p1;  // k=0: same addr, same value
        o2[m] = p2;
    }
    if (t == 0) {  // k = 2048 self-mirror: F1 = Re(Z), F2 = Im(Z)
        f2 z = buf[PHYS(2048)];
        o1[2048] = z.x * z.x;
        o2[2048] = z.y * z.y;
    }
}

extern "C" void kernel_launch(void* const* d_in, const int* in_sizes, int n_in,
                              void* d_out, int out_size, void* d_ws, size_t ws_size,
                              hipStream_t stream) {
    const float* x = (const float*)d_in[0];
    float* out = (float*)d_out;
    const int B = in_sizes[0] / FFT_N;  // 8192
    spec_fft_kernel<<<B / 2, NT, 0, stream>>>(x, out);
}